// Round 6
// baseline (170.759 us; speedup 1.0000x reference)
//
#include <hip/hip_runtime.h>
#include <hip/hip_bf16.h>

#define B_    8
#define O_    4
#define L_    1024
#define E_    1024
#define BETA_ 512
#define NSEG_ 12
#define BO_   32
#define NCH_  32   // k1: 32-row chunks, 32 per bo

// ---- workspace layout (float offsets). NO zero-init needed anywhere.
enum : size_t {
  WS_SPART = 0,                                        // [32][32][12][1024] (sparse: only overlapping slices written)
  WS_X     = WS_SPART + (size_t)BO_ * NCH_ * 12 * E_,  // [32][13][1024]
  WS_P1P   = WS_X     + (size_t)BO_ * 13 * E_,         // [8][32][13][1024]
  WS_TE    = WS_P1P   + (size_t)8  * BO_ * 13 * E_,    // [32][13][1024]  1+relu(P1+bp)
  WS_H1P   = WS_TE    + (size_t)BO_ * 13 * E_,         // [16][32][10][512]
  WS_H1R   = WS_H1P   + (size_t)16 * BO_ * 10 * BETA_, // [32][10][512]
  WS_T1P   = WS_H1R   + (size_t)BO_ * 10 * BETA_,      // [8][32][10][512]
  WS_T1B   = WS_T1P   + (size_t)8  * BO_ * 10 * BETA_, // [32][10][512]  biased logits
  WS_IAB   = WS_T1B   + (size_t)BO_ * 10 * BETA_,      // [32][1024]
  WS_H2P   = WS_IAB   + (size_t)BO_ * 2 * BETA_,       // [8][32][512]
  WS_H2R   = WS_H2P   + (size_t)8  * BO_ * BETA_,      // [32][512]
  WS_T2P   = WS_H2R   + (size_t)BO_ * BETA_,           // [8][32][512]
  WS_RN    = WS_T2P   + (size_t)8  * BO_ * BETA_,      // [32][10][1024]
  WS_H3P   = WS_RN    + (size_t)BO_ * 10 * E_,         // [16][32][10][512]
  WS_H3R   = WS_H3P   + (size_t)16 * BO_ * 10 * BETA_, // [32][10][512]
  WS_T3P   = WS_H3R   + (size_t)BO_ * 10 * BETA_,      // [8][32][10][512]
  WS_CAT   = WS_T3P   + (size_t)8  * BO_ * 10 * BETA_, // [32][4096]
  WS_HFP   = WS_CAT   + (size_t)BO_ * 8 * BETA_,       // [32][32][512]
  WS_END   = WS_HFP   + (size_t)32 * BO_ * BETA_,
};

__device__ __forceinline__ float relu_(float v) { return v > 0.f ? v : 0.f; }

// ---------------- K1: overlap-aware per-chunk segment partial sums --------------------
__global__ void k1_segsum(const float* __restrict__ hidden, const int* __restrict__ idx,
                          float* __restrict__ Spart) {
    const int chunk = blockIdx.x;  // 0..31, 32 rows each
    const int bo = blockIdx.y;
    const int b = bo >> 2;
    int cuts[13];
    cuts[0] = 1;
#pragma unroll
    for (int i = 0; i < 12; ++i) cuts[i + 1] = idx[b * NSEG_ + i];
    const int l0 = chunk * 32;
    const int l1 = l0 + 32;
    int lo = l0 < 1 ? 1 : l0;
    const int hi = l1 < cuts[12] ? l1 : cuts[12];
    if (lo >= hi) return;
    const int e4 = threadIdx.x << 2;
    const float* base = hidden + (size_t)bo * (L_ * E_) + e4;
    float* sp = Spart + (size_t)(bo * NCH_ + chunk) * 12 * E_ + e4;
    int j = 0;
    while (j < 11 && cuts[j + 1] <= lo) ++j;
    int l = lo;
    while (l < hi) {
        const int e2 = (j < 11 && cuts[j + 1] < hi) ? cuts[j + 1] : hi;
        float sx = 0.f, sy = 0.f, sz = 0.f, sw = 0.f;
        for (; l < e2; ++l) {
            const float4 v = *reinterpret_cast<const float4*>(base + (size_t)l * E_);
            sx += v.x; sy += v.y; sz += v.z; sw += v.w;
        }
        float4 s; s.x = sx; s.y = sy; s.z = sz; s.w = sw;
        *reinterpret_cast<float4*>(sp + (size_t)j * E_) = s;  // only intersecting (chunk,seg)
        ++j;
    }
}

// ---------------- K2: reduce intersecting chunk partials -> means X[32][13][1024] -----
__global__ __launch_bounds__(256) void k2_means(
    const float* __restrict__ Spart, const int* __restrict__ idx,
    float* __restrict__ X) {
    const int bo = blockIdx.y;
    const int col = blockIdx.x * 256 + threadIdx.x;
    const int b = bo >> 2;
    int cuts[13];
    cuts[0] = 1;
#pragma unroll
    for (int i = 0; i < 12; ++i) cuts[i + 1] = idx[b * NSEG_ + i];
    const float* sp = Spart + (size_t)bo * NCH_ * 12 * E_ + col;
    float allc = 0.f;
#pragma unroll
    for (int m = 0; m < 12; ++m) {
        const int c0 = cuts[m] >> 5;
        const int c1 = (cuts[m + 1] - 1) >> 5;
        float s = 0.f;
        for (int ch = c0; ch <= c1; ++ch) s += sp[((size_t)ch * 12 + m) * E_];
        X[((size_t)bo * 13 + m) * E_ + col] = s / (float)(cuts[m + 1] - cuts[m]);
        if (m < 10) allc += s;
    }
    X[((size_t)bo * 13 + 12) * E_ + col] = allc / (float)(cuts[10] - 1);
}

// ---------------- uniform-x split-K GEMM: no LDS, x via wave-uniform loads ------------
// OUTP[((kidx*32 + bo)*M + m)*N + c] = sum_{k in [k0,k0+KC)} XR[(bo*XM+m)*K+k] * W[k*N+c]
template<int M, int XM, int K, int N, int KC, int BOG>
__global__ __launch_bounds__(256) void gemm_u(
    const float* __restrict__ XR, const float* __restrict__ W,
    float* __restrict__ OUTP) {
    const int kidx = blockIdx.x;
    const int k0 = kidx * KC;
    const int bo0 = blockIdx.y * BOG;
    const int c = blockIdx.z * 256 + threadIdx.x;
    float acc[BOG][M];
#pragma unroll
    for (int b = 0; b < BOG; ++b)
#pragma unroll
        for (int m = 0; m < M; ++m) acc[b][m] = 0.f;
    const float* __restrict__ wp = W + (size_t)k0 * N + c;
    for (int k4 = 0; k4 < KC / 4; ++k4) {
        const float w0 = wp[(size_t)(4 * k4 + 0) * N];
        const float w1 = wp[(size_t)(4 * k4 + 1) * N];
        const float w2 = wp[(size_t)(4 * k4 + 2) * N];
        const float w3 = wp[(size_t)(4 * k4 + 3) * N];
#pragma unroll
        for (int b = 0; b < BOG; ++b) {
#pragma unroll
            for (int m = 0; m < M; ++m) {
                // wave-uniform address -> scalarized (s_load) or L1-broadcast
                const float4 xv = *reinterpret_cast<const float4*>(
                    XR + ((size_t)(bo0 + b) * XM + m) * K + k0 + 4 * k4);
                float a = acc[b][m];
                a = fmaf(xv.x, w0, a);
                a = fmaf(xv.y, w1, a);
                a = fmaf(xv.z, w2, a);
                a = fmaf(xv.w, w3, a);
                acc[b][m] = a;
            }
        }
    }
#pragma unroll
    for (int b = 0; b < BOG; ++b) {
        float* op = OUTP + (((size_t)kidx * BO_ + bo0 + b) * M) * N + c;
#pragma unroll
        for (int m = 0; m < M; ++m) op[(size_t)m * N] = acc[b][m];
    }
}

// ---------------- t_te: TE = 1+relu(sum P1P + bp); also fills CAT rows 10..12 ---------
__global__ __launch_bounds__(256) void t_te(
    const float* __restrict__ P1P, const float* __restrict__ bp,
    float* __restrict__ TE, float* __restrict__ CAT) {
    const int bo = blockIdx.y;
    const int i = blockIdx.x * 256 + threadIdx.x;  // < 13*1024
    const int m = i >> 10, col = i & 1023;
    float s = bp[col];
#pragma unroll
    for (int p = 0; p < 8; ++p)
        s += P1P[(((size_t)p * BO_ + bo) * 13 + m) * E_ + col];
    const float v = 1.f + relu_(s);
    TE[((size_t)bo * 13 + m) * E_ + col] = v;
    if (m >= 10) CAT[(size_t)bo * 4096 + (size_t)(13 - m) * 1024 + col] = v;
}

// ---------------- t_hrelu: HR = relu(sum_p HP + b) ------------------------------------
template<int NPART, int ROWS>
__global__ __launch_bounds__(256) void t_hrelu(
    const float* __restrict__ HP, const float* __restrict__ b,
    float* __restrict__ HR) {
    const int bo = blockIdx.y;
    const int i = blockIdx.x * 256 + threadIdx.x;  // < ROWS*512
    const int col = i & 511;
    float s = b[col];
#pragma unroll
    for (int p = 0; p < NPART; ++p)
        s += HP[((size_t)p * BO_ + bo) * (ROWS * BETA_) + i];
    HR[(size_t)bo * (ROWS * BETA_) + i] = relu_(s);
}

// ---------------- t_iab: pool-1 logits + softmax -> T1B, IAB --------------------------
__global__ void __launch_bounds__(512) t_iab(
    const float* __restrict__ T1P, const float* __restrict__ ba,
    const float* __restrict__ TE, float* __restrict__ T1B,
    float* __restrict__ IAB) {
    const int bo = blockIdx.x;
    const int c = threadIdx.x;  // 0..511
    const float bac = ba[c];
    float t[10], mx = -1e30f;
#pragma unroll
    for (int j = 0; j < 10; ++j) {
        float s = bac;
#pragma unroll
        for (int p = 0; p < 8; ++p)
            s += T1P[(((size_t)p * BO_ + bo) * 10 + j) * BETA_ + c];
        t[j] = s;
        T1B[((size_t)bo * 10 + j) * BETA_ + c] = s;
        mx = fmaxf(mx, s);
    }
    float p[10], sw = 0.f;
#pragma unroll
    for (int j = 0; j < 10; ++j) { p[j] = expf(t[j] - mx); sw += p[j]; }
    const float inv = 1.0f / sw;
    float ia = 0.f, ib = 0.f;
#pragma unroll
    for (int j = 0; j < 10; ++j) {
        const float pj = p[j] * inv;
        ia = fmaf(pj, TE[((size_t)bo * 13 + j) * E_ + c], ia);
        ib = fmaf(pj, TE[((size_t)bo * 13 + j) * E_ + BETA_ + c], ib);
    }
    IAB[(size_t)bo * 1024 + c] = ia;
    IAB[(size_t)bo * 1024 + BETA_ + c] = ib;
}

// ---------------- t_rn: pool-2 2-way softmax -> RN ------------------------------------
__global__ __launch_bounds__(256) void t_rn(
    const float* __restrict__ T1B, const float* __restrict__ T2P,
    const float* __restrict__ ba, const float* __restrict__ TE,
    const float* __restrict__ IAB, float* __restrict__ RN) {
    const int bo = blockIdx.y;
    const int i = blockIdx.x * 256 + threadIdx.x;  // j*1024 + k
    const int j = i >> 10, k = i & 1023;
    const int col = k & 511;
    const float tj = T1B[((size_t)bo * 10 + j) * BETA_ + col];
    float tI = ba[col];
#pragma unroll
    for (int p = 0; p < 8; ++p)
        tI += T2P[((size_t)p * BO_ + bo) * BETA_ + col];
    const float mx = fmaxf(tj, tI);
    const float e0 = expf(tj - mx);
    const float e1 = expf(tI - mx);
    const float ea = TE[((size_t)bo * 13 + j) * E_ + k];
    const float iv = IAB[(size_t)bo * 1024 + k];
    RN[((size_t)bo * 10 + j) * E_ + k] = (e0 + e1) / (e0 * ea + e1 * iv);
}

// ---------------- t_cat: pool-3 softmax -> CAT cols 0..1023 ---------------------------
__global__ __launch_bounds__(256) void t_cat(
    const float* __restrict__ T3P, const float* __restrict__ ba,
    const float* __restrict__ RN, float* __restrict__ CAT) {
    const int bo = blockIdx.y;
    const int k = blockIdx.x * 256 + threadIdx.x;  // < 1024
    const int col = k & 511;
    const float bac = ba[col];
    float t[10], mx = -1e30f;
#pragma unroll
    for (int j = 0; j < 10; ++j) {
        float s = bac;
#pragma unroll
        for (int p = 0; p < 8; ++p)
            s += T3P[(((size_t)p * BO_ + bo) * 10 + j) * BETA_ + col];
        t[j] = s;
        mx = fmaxf(mx, s);
    }
    float sw = 0.f, acc = 0.f;
#pragma unroll
    for (int j = 0; j < 10; ++j) {
        const float pj = expf(t[j] - mx);
        sw += pj;
        acc = fmaf(pj, RN[((size_t)bo * 10 + j) * E_ + k], acc);
    }
    CAT[(size_t)bo * 4096 + k] = sw / acc;
}

// ---------------- final: out[bo] = relu(sum_p HFpart + bl0) . Wl + bl -----------------
__global__ void __launch_bounds__(512) k_final(
    const float* __restrict__ HFP, const float* __restrict__ bl0,
    const float* __restrict__ Wl, const float* __restrict__ bl,
    float* __restrict__ out) {
    const int bo = blockIdx.x;
    const int c = threadIdx.x;
    float s = bl0[c];
#pragma unroll
    for (int p = 0; p < 32; ++p) s += HFP[((size_t)p * BO_ + bo) * BETA_ + c];
    float partial = relu_(s) * Wl[c];
#pragma unroll
    for (int off = 32; off > 0; off >>= 1) partial += __shfl_down(partial, off, 64);
    __shared__ float red[8];
    if ((c & 63) == 0) red[c >> 6] = partial;
    __syncthreads();
    if (c == 0) out[bo] = red[0] + red[1] + red[2] + red[3] + red[4] + red[5] + red[6] + red[7] + bl[0];
}

extern "C" void kernel_launch(void* const* d_in, const int* in_sizes, int n_in,
                              void* d_out, int out_size, void* d_ws, size_t ws_size,
                              hipStream_t stream) {
    const float* hidden = (const float*)d_in[0];
    const int* idx = (const int*)d_in[1];
    const float* Wp  = (const float*)d_in[2];
    const float* bp  = (const float*)d_in[3];
    const float* Wa0 = (const float*)d_in[4];
    const float* ba0 = (const float*)d_in[5];
    const float* Wa  = (const float*)d_in[6];
    const float* ba  = (const float*)d_in[7];
    const float* Wl0 = (const float*)d_in[8];
    const float* bl0 = (const float*)d_in[9];
    const float* Wl  = (const float*)d_in[10];
    const float* bl  = (const float*)d_in[11];
    float* ws = (float*)d_ws;
    float* SPART = ws + WS_SPART;
    float* X     = ws + WS_X;
    float* P1P   = ws + WS_P1P;
    float* TE    = ws + WS_TE;
    float* H1P   = ws + WS_H1P;
    float* H1R   = ws + WS_H1R;
    float* T1P   = ws + WS_T1P;
    float* T1B   = ws + WS_T1B;
    float* IAB   = ws + WS_IAB;
    float* H2P   = ws + WS_H2P;
    float* H2R   = ws + WS_H2R;
    float* T2P   = ws + WS_T2P;
    float* RN    = ws + WS_RN;
    float* H3P   = ws + WS_H3P;
    float* H3R   = ws + WS_H3R;
    float* T3P   = ws + WS_T3P;
    float* CAT   = ws + WS_CAT;
    float* HFP   = ws + WS_HFP;

    k1_segsum<<<dim3(NCH_, BO_), 256, 0, stream>>>(hidden, idx, SPART);
    k2_means<<<dim3(4, BO_), 256, 0, stream>>>(SPART, idx, X);
    // G1: P1P[8] = X @ Wp  (M=13, K=1024, N=1024)
    gemm_u<13, 13, 1024, 1024, 128, 2>
        <<<dim3(8, 16, 4), 256, 0, stream>>>(X, Wp, P1P);
    t_te<<<dim3(52, BO_), 256, 0, stream>>>(P1P, bp, TE, CAT);
    // G2: H1P[16] = TE(rows 0..9) @ Wa0
    gemm_u<10, 13, 1024, 512, 64, 2>
        <<<dim3(16, 16, 2), 256, 0, stream>>>(TE, Wa0, H1P);
    t_hrelu<16, 10><<<dim3(20, BO_), 256, 0, stream>>>(H1P, ba0, H1R);
    // G3: T1P[8] = H1R @ Wa
    gemm_u<10, 10, 512, 512, 64, 2>
        <<<dim3(8, 16, 2), 256, 0, stream>>>(H1R, Wa, T1P);
    t_iab<<<BO_, 512, 0, stream>>>(T1P, ba, TE, T1B, IAB);
    // G4: H2P[8] = IAB @ Wa0
    gemm_u<1, 1, 1024, 512, 128, 2>
        <<<dim3(8, 16, 2), 256, 0, stream>>>(IAB, Wa0, H2P);
    t_hrelu<8, 1><<<dim3(2, BO_), 256, 0, stream>>>(H2P, ba0, H2R);
    // G5: T2P[8] = H2R @ Wa
    gemm_u<1, 1, 512, 512, 64, 2>
        <<<dim3(8, 16, 2), 256, 0, stream>>>(H2R, Wa, T2P);
    t_rn<<<dim3(40, BO_), 256, 0, stream>>>(T1B, T2P, ba, TE, IAB, RN);
    // G6: H3P[16] = RN @ Wa0
    gemm_u<10, 10, 1024, 512, 64, 2>
        <<<dim3(16, 16, 2), 256, 0, stream>>>(RN, Wa0, H3P);
    t_hrelu<16, 10><<<dim3(20, BO_), 256, 0, stream>>>(H3P, ba0, H3R);
    // G7: T3P[8] = H3R @ Wa
    gemm_u<10, 10, 512, 512, 64, 2>
        <<<dim3(8, 16, 2), 256, 0, stream>>>(H3R, Wa, T3P);
    t_cat<<<dim3(4, BO_), 256, 0, stream>>>(T3P, ba, RN, CAT);
    // G8: HFP[32] = CAT @ Wl0  (K=4096)
    gemm_u<1, 1, 4096, 512, 128, 8>
        <<<dim3(32, 4, 2), 256, 0, stream>>>(CAT, Wl0, HFP);
    k_final<<<BO_, 512, 0, stream>>>(HFP, bl0, Wl, bl, (float*)d_out);
}